// Round 2
// baseline (298.332 us; speedup 1.0000x reference)
//
#include <hip/hip_runtime.h>

// TaylorExp feature map, d=16:
//   out[row, 0]             = 1
//   out[row, 1..16]         = x[row, i] * 0.5                      (1/rrd, rrd=2)
//   out[row, 17 + i*16 + j] = x[row,i]*x[row,j] * (1/(4*sqrt(2)))
//
// Memory-bound (writes ~17x reads). v2 strategy: decouple compute from the
// write stream. Phase 1 computes the block's contiguous 4368-float output
// chunk into LDS with a structured (row, j)-per-thread mapping — no integer
// divides, no segment selects, broadcast LDS reads only. Phase 2 streams the
// chunk out as pure ds_read_b128 -> global_store_dwordx4 copies.

#define D               16
#define OUTD            273          // 1 + 16 + 256
#define ROWS_PER_BLOCK  16
#define THREADS         256
#define CHUNK           (OUTD * ROWS_PER_BLOCK)   // 4368 floats per block
#define CHUNK4          (CHUNK / 4)               // 1092 float4 per block

__global__ __launch_bounds__(THREADS)
void taylor_exp_kernel(const float* __restrict__ x,
                       float* __restrict__ out,
                       int nrows) {
    __shared__ __align__(16) float xs[ROWS_PER_BLOCK * D];   // 1 KB
    __shared__ __align__(16) float tile[CHUNK];              // 17472 B

    const int tid = threadIdx.x;
    const long long rowBase = (long long)blockIdx.x * ROWS_PER_BLOCK;

    // ---- Phase 0: stage 16 rows x 16 floats (one coalesced 1 KB load) ----
    {
        const int localRow = tid >> 4;
        float v = 0.0f;
        if (rowBase + localRow < (long long)nrows) {
            v = x[rowBase * D + tid];
        }
        xs[tid] = v;
    }
    __syncthreads();

    // ---- Phase 1: compute the 16x273 output chunk into LDS ----
    // Thread (row = tid>>4, l = tid&15) owns quad-column jj = (l+15)&15 of its
    // row: elements out[row, 17 + 16*s + jj] = x[s]*x[jj]*S2 for s = 0..15,
    // plus the linear element out[row, 1+jj] = x[jj]*0.5, plus (l==0) the 1.
    {
        const int row = tid >> 4;
        const int l   = tid & 15;
        const int jj  = (l + 15) & 15;          // l==0 -> 15, else l-1
        const float S2 = 0.17677669529663688f;  // 1/(4*sqrt(2))

        const float* __restrict__ xr = &xs[row * D];
        float* __restrict__ tr = &tile[row * OUTD];

        const float xj = xr[jj];                // 1 scalar LDS read (16 distinct addrs/row-group)
        if (l == 0) tr[0] = 1.0f;
        tr[1 + jj] = xj * 0.5f;

        const float xj2 = xj * S2;
        // Row vector via 4 broadcast ds_read_b128 (same addr across the row's 16 lanes).
        const float4 a0 = reinterpret_cast<const float4*>(xr)[0];
        const float4 a1 = reinterpret_cast<const float4*>(xr)[1];
        const float4 a2 = reinterpret_cast<const float4*>(xr)[2];
        const float4 a3 = reinterpret_cast<const float4*>(xr)[3];
        const float xv[16] = {a0.x, a0.y, a0.z, a0.w,  a1.x, a1.y, a1.z, a1.w,
                              a2.x, a2.y, a2.z, a2.w,  a3.x, a3.y, a3.z, a3.w};
        float* __restrict__ trq = tr + 17 + jj;
#pragma unroll
        for (int s = 0; s < 16; ++s) {
            // Writes: fixed s, the 16 lanes of a row hit 16 consecutive banks;
            // the 4 rows of a wave alias <=2-3-way (273 mod 32 = 17) -> ~free.
            trq[16 * s] = xv[s] * xj2;
        }
    }
    __syncthreads();

    // ---- Phase 2: stream the contiguous 4368-float chunk to global ----
    const long long outBase = rowBase * OUTD;            // multiple of 4368 -> 16B-aligned
    const long long totalOut = (long long)nrows * OUTD;
    const float4* __restrict__ t4 = reinterpret_cast<const float4*>(tile);
    float4* __restrict__ o4 = reinterpret_cast<float4*>(out) + (outBase >> 2);

    if (outBase + CHUNK <= totalOut) {
        // Full block: unguarded ds_read_b128 -> dwordx4 store, 1 KB/wave/instr.
#pragma unroll
        for (int n = 0; n < 5; ++n) {
            const int t = tid + n * THREADS;
            if (n < 4 || t < CHUNK4) {
                o4[t] = t4[t];
            }
        }
    } else {
        // Ragged tail block (only if nrows % ROWS_PER_BLOCK != 0).
        for (int t = tid; t < CHUNK4; t += THREADS) {
            const long long gi = outBase + 4ll * t;
            const float4 v = t4[t];
            const float tmp[4] = {v.x, v.y, v.z, v.w};
#pragma unroll
            for (int e = 0; e < 4; ++e) {
                if (gi + e < totalOut) out[gi + e] = tmp[e];
            }
        }
    }
}

extern "C" void kernel_launch(void* const* d_in, const int* in_sizes, int n_in,
                              void* d_out, int out_size, void* d_ws, size_t ws_size,
                              hipStream_t stream) {
    const float* x = (const float*)d_in[0];
    float* out = (float*)d_out;

    const int n = in_sizes[0];        // total x elements
    const int nrows = n / D;          // 262144 for the bench shape
    const int blocks = (nrows + ROWS_PER_BLOCK - 1) / ROWS_PER_BLOCK;

    taylor_exp_kernel<<<dim3(blocks), dim3(THREADS), 0, stream>>>(x, out, nrows);
}